// Round 9
// baseline (346.963 us; speedup 1.0000x reference)
//
#include <hip/hip_runtime.h>
#include <hip/hip_fp16.h>

#define N_GRAPHS_C 256
#define CHUNK_LOG 12
#define CHUNK (1 << CHUNK_LOG)   // 4096 atoms per bucket
#define MAXB 64
#define NSLICE 12                // passB slices per bucket
#define NSLICE_FB 10
#define TPA 256
#define TPBB 1024                // 49 KB LDS -> 2 blocks x 16 waves = 32 waves/CU
#define SD 64                    // LDS staging depth per bucket (mean 42/phase, +3.5 sigma)
#define SSTR (2 * SD + 1)        // stage dword stride: 129 odd -> banks (b+2r)%32
#define PSTR (CHUNK + 8)         // passB plane stride: banks idx, idx+8, idx+16
#define FP_SCALE 1024.0f
#define FP_INV   (1.0f / 1024.0f)

// ---------------- shared per-edge math ----------------
// Units: Angstrom, electron charge, eV (avoids fp32 denormals from the
// reference's SI-unit charges; algebraically identical).
__device__ __forceinline__ void edge_math(
    float dx, float dy, float dz, float qr, float qc, float gA,
    float& fx, float& fy, float& fz, float& ecoul)
{
    const float KEV = (float)(8987551792.3 * 1.602176634e-9); // 14.3996 eV*A/e^2
    float r2 = dx * dx + dy * dy + dz * dz;
    float inv_r = rsqrtf(r2);
    float rA = r2 * inv_r;

    float pref = KEV * qr * qc * inv_r;

    float damp = 1.0f;
    if (rA < 2.2f)
        damp = __expf(-18.7f * (2.2f - rA) * (1.0f / 2.2f));

    float grij = gA * rA;
    float expm2 = __expf(-grij * grij);
    float t = 1.0f / (1.0f + 0.3275911f * grij);
    float erfc = t * (0.254829592f +
                 t * (-0.284496736f +
                 t * (1.421413741f +
                 t * (-1.453152027f +
                 t * 1.061405429f)))) * expm2;

    ecoul = pref * (0.5f * damp + (erfc - 1.0f));
    float S = damp + erfc + 2.0f * grij * expm2 - 1.0f;
    float fs = pref * S * (inv_r * inv_r);
    fx = dx * fs; fy = dy * fs; fz = dz * fs;
}

__device__ __forceinline__ uint2 pack_rec(float fx, float fy, float fz, unsigned lid)
{
    uint2 u;
    u.x = __builtin_bit_cast(unsigned, __floats2half2_rn(fx, fy));
    u.y = (__builtin_bit_cast(unsigned, __floats2half2_rn(fz, 0.0f)) & 0xFFFFu) |
          (lid << 16);
    return u;
}

// passB record accumulate: f16 record -> i32 fixed-point (scale 2^10) into
// three PADDED planes (stride CHUNK+8) via native integer LDS atomics.
// Unpadded (stride 4096 = 0 mod 32 banks) all 3 atomics of a record hit the
// SAME bank (r7 diagnosis). Padded: banks idx, idx+8, idx+16.
__device__ __forceinline__ void acc_rec(int* acc, unsigned w0, unsigned w1)
{
    float2 xy = __half22float2(__builtin_bit_cast(__half2, w0));
    float fz = __half2float(__builtin_bit_cast(__half2, w1).x);   // low half
    unsigned idx = w1 >> 16;
    atomicAdd(&acc[idx],            __float2int_rn(xy.x * FP_SCALE));
    atomicAdd(&acc[PSTR + idx],     __float2int_rn(xy.y * FP_SCALE));
    atomicAdd(&acc[2 * PSTR + idx], __float2int_rn(fz   * FP_SCALE));
}

// prep: fuse q[] and batch[] into one 8 B table; zero ovf[] and the global
// i32 force planes fint[3][n_atoms] (replaces memset launches).
__global__ __launch_bounds__(256) void prep_qg(
    const float* __restrict__ q, const int* __restrict__ batch,
    float2* __restrict__ qg, float* __restrict__ ovf, int* __restrict__ fint,
    int n_atoms)
{
    int i = blockIdx.x * 256 + threadIdx.x;
    if (i < n_atoms) {
        qg[i] = make_float2(q[i], __int_as_float(batch[i]));
        ovf[3 * i + 0] = 0.f;
        ovf[3 * i + 1] = 0.f;
        ovf[3 * i + 2] = 0.f;
        fint[i] = 0;
        fint[n_atoms + i] = 0;
        fint[2 * n_atoms + i] = 0;
    }
}

// ================= fast path =================
// passA with LDS-staged coalesced record flush (r6: -38us vs scattered
// stores). Stage is a flat unsigned array with ODD dword stride 129: append
// of record rank r into bucket b lands in banks (b*129+2r)%32 = (b+2r)%32,
// spreading concurrent same-rank appends across all 32 banks (the r6 SD+1
// uint2 pad only reached even bank-pairs -- 5M residual conflicts).
__global__ __launch_bounds__(TPA) void passA(
    const float* __restrict__ dij, const float2* __restrict__ qg,
    const float* __restrict__ g_ewald,
    const int* __restrict__ row, const int* __restrict__ col,
    uint2* __restrict__ records, int cap,
    unsigned* __restrict__ cnt_table,
    float* __restrict__ e_part,
    float* __restrict__ ovf,
    int n_edges, int nb, int tile_g)
{
    __shared__ unsigned stageU[MAXB * SSTR];    // 33 KB, odd-stride staging
    __shared__ unsigned scnt[MAXB];             // per-phase stage counts
    __shared__ unsigned cnt[MAXB];              // per-block reserved slots
    __shared__ float    e_graph[4 * N_GRAPHS_C];

    int tid  = threadIdx.x;
    int wid  = tid >> 6;
    int lane = tid & 63;
    if (tid < MAXB) { scnt[tid] = 0u; cnt[tid] = 0u; }
    for (int i = tid; i < 4 * N_GRAPHS_C; i += TPA) e_graph[i] = 0.f;
    __syncthreads();

    float* e_my = &e_graph[wid * N_GRAPHS_C];

    int n4 = n_edges >> 2;
    int gbase = blockIdx.x * tile_g;
    int g1 = min(gbase + tile_g, n4);
    int nph = tile_g / TPA;

    const int4* row4 = (const int4*)row;
    const int4* col4 = (const int4*)col;
    const float4* dij4 = (const float4*)dij;

    const float gA = g_ewald[0] * 1e-10f;    // 1/m -> 1/Angstrom
    size_t blk_base = (size_t)blockIdx.x * nb * cap;

    // prologue: indices + gathers for phase 0
    int4 r_cur = make_int4(0, 0, 0, 0), c_cur = make_int4(0, 0, 0, 0);
    float2 vr_cur[4], vc_cur[4];
    {
        int g = gbase + tid;
        if (g < g1) { r_cur = row4[g]; c_cur = col4[g]; }
        vr_cur[0] = qg[r_cur.x]; vc_cur[0] = qg[c_cur.x];
        vr_cur[1] = qg[r_cur.y]; vc_cur[1] = qg[c_cur.y];
        vr_cur[2] = qg[r_cur.z]; vc_cur[2] = qg[c_cur.z];
        vr_cur[3] = qg[r_cur.w]; vc_cur[3] = qg[c_cur.w];
    }

    for (int p = 0; p < nph; ++p) {
        int g = gbase + p * TPA + tid;

        // next phase's indices (issued early; qg[0] dummies past the end)
        int4 r_nxt = make_int4(0, 0, 0, 0), c_nxt = make_int4(0, 0, 0, 0);
        if (p + 1 < nph && g + TPA < g1) {
            r_nxt = row4[g + TPA]; c_nxt = col4[g + TPA];
        }

        if (g < g1) {
            float4 d0 = dij4[3 * g + 0];
            float4 d1 = dij4[3 * g + 1];
            float4 d2 = dij4[3 * g + 2];
            float ex[4] = {d0.x, d0.w, d1.z, d2.y};
            float ey[4] = {d0.y, d1.x, d1.w, d2.z};
            float ez[4] = {d0.z, d1.y, d2.x, d2.w};
            int rr[4] = {r_cur.x, r_cur.y, r_cur.z, r_cur.w};
            int cc[4] = {c_cur.x, c_cur.y, c_cur.z, c_cur.w};

            #pragma unroll
            for (int j = 0; j < 4; ++j) {
                int r = rr[j], c = cc[j];
                float fx, fy, fz, ec;
                edge_math(ex[j], ey[j], ez[j], vr_cur[j].x, vc_cur[j].x, gA,
                          fx, fy, fz, ec);

                atomicAdd(&e_my[__float_as_int(vr_cur[j].y)], ec);

                int br = r >> CHUNK_LOG, bc = c >> CHUNK_LOG;
                unsigned pr = atomicAdd(&scnt[br], 1u);
                unsigned pc = atomicAdd(&scnt[bc], 1u);
                if (pr < SD) {
                    uint2 rv = pack_rec(fx, fy, fz, (unsigned)(r & (CHUNK - 1)));
                    int bi = br * SSTR + 2 * (int)pr;
                    stageU[bi] = rv.x; stageU[bi + 1] = rv.y;
                } else {
                    atomicAdd(&ovf[3 * r + 0], fx);
                    atomicAdd(&ovf[3 * r + 1], fy);
                    atomicAdd(&ovf[3 * r + 2], fz);
                }
                if (pc < SD) {
                    uint2 rv = pack_rec(-fx, -fy, -fz, (unsigned)(c & (CHUNK - 1)));
                    int bi = bc * SSTR + 2 * (int)pc;
                    stageU[bi] = rv.x; stageU[bi + 1] = rv.y;
                } else {
                    atomicAdd(&ovf[3 * c + 0], -fx);
                    atomicAdd(&ovf[3 * c + 1], -fy);
                    atomicAdd(&ovf[3 * c + 2], -fz);
                }
            }
        }

        // issue next phase's gathers now: latency hides under the flush
        float2 vr_n[4], vc_n[4];
        vr_n[0] = qg[r_nxt.x]; vc_n[0] = qg[c_nxt.x];
        vr_n[1] = qg[r_nxt.y]; vc_n[1] = qg[c_nxt.y];
        vr_n[2] = qg[r_nxt.z]; vc_n[2] = qg[c_nxt.z];
        vr_n[3] = qg[r_nxt.w]; vc_n[3] = qg[c_nxt.w];

        __syncthreads();

        // wave-cooperative flush: wave handles buckets wid, wid+4, ...
        for (int b = wid; b < nb; b += TPA / 64) {
            unsigned m = min(scnt[b], (unsigned)SD);
            unsigned base = 0;
            if (lane == 0) base = atomicAdd(&cnt[b], m);
            base = (unsigned)__shfl((int)base, 0, 64);
            int sb = b * SSTR;
            for (unsigned i = lane; i < m; i += 64) {
                uint2 rv = make_uint2(stageU[sb + 2 * i], stageU[sb + 2 * i + 1]);
                unsigned slot = base + i;
                if (slot < (unsigned)cap) {
                    records[blk_base + (size_t)b * cap + slot] = rv;
                } else {
                    float2 xy = __half22float2(__builtin_bit_cast(__half2, rv.x));
                    float fzv = __half2float(__builtin_bit_cast(__half2, rv.y).x);
                    int atom = (b << CHUNK_LOG) + (int)(rv.y >> 16);
                    atomicAdd(&ovf[3 * atom + 0], xy.x);
                    atomicAdd(&ovf[3 * atom + 1], xy.y);
                    atomicAdd(&ovf[3 * atom + 2], fzv);
                }
            }
            if (lane == 0) scnt[b] = 0u;
        }
        __syncthreads();

        r_cur = r_nxt; c_cur = c_nxt;
        #pragma unroll
        for (int j = 0; j < 4; ++j) { vr_cur[j] = vr_n[j]; vc_cur[j] = vc_n[j]; }
    }

    if (tid < nb) cnt_table[(size_t)blockIdx.x * nb + tid] = min(cnt[tid], (unsigned)cap);
    for (int g2 = tid; g2 < N_GRAPHS_C; g2 += TPA)
        e_part[(size_t)blockIdx.x * N_GRAPHS_C + g2] =
            e_graph[g2] + e_graph[N_GRAPHS_C + g2] +
            e_graph[2 * N_GRAPHS_C + g2] + e_graph[3 * N_GRAPHS_C + g2];
}

// passB: block (b,s). 4 runs concurrently per wave, exec-masked native-i32
// accumulates into bank-padded LDS planes. Epilogue: sparse global integer
// atomicAdd into fint[3][n_atoms] (L2-resident 2.4 MB, ~12 adds/address,
// exact and deterministic) -- replaces the 29 MB partial write + 29 MB
// fin_force re-read of r8. TPBB=1024: 2 blocks x 16 waves = 32 waves/CU.
__global__ __launch_bounds__(TPBB) void passB(
    const uint2* __restrict__ records, int cap,
    const unsigned* __restrict__ cnt_table,
    int* __restrict__ fint, int nblkA, int nb, int nslice, int n_atoms)
{
    __shared__ int acc[3 * PSTR];

    int b = blockIdx.x / nslice;
    int s = blockIdx.x % nslice;
    int k0 = (int)((long long)s * nblkA / nslice);
    int k1 = (int)((long long)(s + 1) * nblkA / nslice);

    for (int i = threadIdx.x; i < 3 * PSTR; i += TPBB) acc[i] = 0;
    __syncthreads();

    int wid  = threadIdx.x >> 6;
    int lane = threadIdx.x & 63;
    const int W = TPBB / 64;                      // 16 waves

    for (int kb = k0 + wid; kb < k1; kb += 4 * W) {
        int ka = kb, kB = kb + W, kc = kb + 2 * W, kd = kb + 3 * W;
        bool e1 = kB < k1, e2 = kc < k1, e3 = kd < k1;

        unsigned n0 = cnt_table[(size_t)ka * nb + b];
        unsigned n1 = e1 ? cnt_table[(size_t)kB * nb + b] : 0u;
        unsigned n2 = e2 ? cnt_table[(size_t)kc * nb + b] : 0u;
        unsigned n3 = e3 ? cnt_table[(size_t)kd * nb + b] : 0u;

        const uint2* r0 = records + ((size_t)ka * nb + b) * cap;
        const uint2* r1 = e1 ? records + ((size_t)kB * nb + b) * cap : r0;
        const uint2* r2 = e2 ? records + ((size_t)kc * nb + b) * cap : r0;
        const uint2* r3 = e3 ? records + ((size_t)kd * nb + b) * cap : r0;
        const uint4* q0 = (const uint4*)r0;
        const uint4* q1 = (const uint4*)r1;
        const uint4* q2 = (const uint4*)r2;
        const uint4* q3 = (const uint4*)r3;

        unsigned h0 = n0 >> 1, h1 = n1 >> 1, h2 = n2 >> 1, h3 = n3 >> 1;
        unsigned hm = max(max(h0, h1), max(h2, h3));

        for (unsigned i = lane; i < hm; i += 64) {
            uint4 v0 = q0[h0 ? min(i, h0 - 1u) : 0u];
            uint4 v1 = q1[h1 ? min(i, h1 - 1u) : 0u];
            uint4 v2 = q2[h2 ? min(i, h2 - 1u) : 0u];
            uint4 v3 = q3[h3 ? min(i, h3 - 1u) : 0u];
            if (i < h0) { acc_rec(acc, v0.x, v0.y); acc_rec(acc, v0.z, v0.w); }
            if (i < h1) { acc_rec(acc, v1.x, v1.y); acc_rec(acc, v1.z, v1.w); }
            if (i < h2) { acc_rec(acc, v2.x, v2.y); acc_rec(acc, v2.z, v2.w); }
            if (i < h3) { acc_rec(acc, v3.x, v3.y); acc_rec(acc, v3.z, v3.w); }
        }
        if (lane == 0) {
            if (n0 & 1u) { uint2 t = r0[n0 - 1]; acc_rec(acc, t.x, t.y); }
            if (n1 & 1u) { uint2 t = r1[n1 - 1]; acc_rec(acc, t.x, t.y); }
            if (n2 & 1u) { uint2 t = r2[n2 - 1]; acc_rec(acc, t.x, t.y); }
            if (n3 & 1u) { uint2 t = r3[n3 - 1]; acc_rec(acc, t.x, t.y); }
        }
    }
    __syncthreads();

    // sparse exact cross-slice reduction via global integer atomics
    int abase = b << CHUNK_LOG;
    for (int i = threadIdx.x; i < 3 * CHUNK; i += TPBB) {
        int pl  = i >> CHUNK_LOG;
        int ofs = i & (CHUNK - 1);
        int v = acc[pl * PSTR + ofs];
        int a = abase + ofs;
        if (v != 0 && a < n_atoms)
            atomicAdd(&fint[pl * n_atoms + a], v);
    }
}

// fin_force: blocks [0,nfblk) convert fint -> force (+ovf); blocks
// [nfblk, nfblk+64) do the energy reduction (one wave per graph).
__global__ __launch_bounds__(256) void fin_force(
    const int* __restrict__ fint, const float* __restrict__ ovf,
    const float* __restrict__ e_part,
    float* __restrict__ force, float* __restrict__ energy,
    int n_atoms, int nblkA, int nfblk)
{
    if ((int)blockIdx.x >= nfblk) {
        int g = (blockIdx.x - nfblk) * 4 + (threadIdx.x >> 6);   // graph per wave
        int lane = threadIdx.x & 63;
        float s = 0.f;
        for (int k = lane; k < nblkA; k += 64)
            s += e_part[(size_t)k * N_GRAPHS_C + g];
        for (int off = 32; off > 0; off >>= 1) s += __shfl_down(s, off, 64);
        if (lane == 0) energy[g] = s;
        return;
    }
    int a = blockIdx.x * 256 + threadIdx.x;
    if (a >= n_atoms) return;
    force[3 * a + 0] = ovf[3 * a + 0] + (float)fint[a] * FP_INV;
    force[3 * a + 1] = ovf[3 * a + 1] + (float)fint[n_atoms + a] * FP_INV;
    force[3 * a + 2] = ovf[3 * a + 2] + (float)fint[2 * n_atoms + a] * FP_INV;
}

// ================= fallback: chunk-scan path =================
__global__ __launch_bounds__(1024) void chunk_kernel(
    const float* __restrict__ dij, const float* __restrict__ q,
    const float* __restrict__ g_ewald,
    const int* __restrict__ row, const int* __restrict__ col,
    float* __restrict__ partial, int n_edges, int n_chunks, int n_slices)
{
    __shared__ float acc[CHUNK * 4];
    int c = blockIdx.x % n_chunks;
    int p = blockIdx.x / n_chunks;
    int cbase = c << CHUNK_LOG;
    for (int i = threadIdx.x; i < CHUNK * 4; i += 1024) acc[i] = 0.f;
    __syncthreads();
    const float gA = g_ewald[0] * 1e-10f;
    int n4 = (n_edges + 3) >> 2;
    int g0 = (int)((long long)p * n4 / n_slices);
    int g1 = (int)((long long)(p + 1) * n4 / n_slices);
    const int4* row4 = (const int4*)row;
    const int4* col4 = (const int4*)col;
    for (int g = g0 + threadIdx.x; g < g1; g += 1024) {
        int4 r4 = row4[g];
        int4 c4 = col4[g];
        int rr[4] = {r4.x, r4.y, r4.z, r4.w};
        int cc[4] = {c4.x, c4.y, c4.z, c4.w};
        #pragma unroll
        for (int j = 0; j < 4; ++j) {
            int e = 4 * g + j;
            if (e >= n_edges) break;
            int rl = rr[j] - cbase;
            int cl = cc[j] - cbase;
            bool hr = (unsigned)rl < (unsigned)CHUNK;
            bool hc = (unsigned)cl < (unsigned)CHUNK;
            if (!(hr || hc)) continue;
            float fx, fy, fz, ec;
            edge_math(dij[3 * e], dij[3 * e + 1], dij[3 * e + 2],
                      q[rr[j]], q[cc[j]], gA, fx, fy, fz, ec);
            if (hr) {
                atomicAdd(&acc[4 * rl + 0], fx);
                atomicAdd(&acc[4 * rl + 1], fy);
                atomicAdd(&acc[4 * rl + 2], fz);
                atomicAdd(&acc[4 * rl + 3], ec);
            }
            if (hc) {
                atomicAdd(&acc[4 * cl + 0], -fx);
                atomicAdd(&acc[4 * cl + 1], -fy);
                atomicAdd(&acc[4 * cl + 2], -fz);
            }
        }
    }
    __syncthreads();
    float4* dst = (float4*)partial + (size_t)(c * n_slices + p) * CHUNK;
    const float4* src = (const float4*)acc;
    for (int i = threadIdx.x; i < CHUNK; i += 1024) dst[i] = src[i];
}

__global__ __launch_bounds__(256) void finalize_kernel(
    const float* __restrict__ partial, const int* __restrict__ batch,
    float* __restrict__ energy, float* __restrict__ force,
    int n_atoms, int n_slices)
{
    int i = blockIdx.x * blockDim.x + threadIdx.x;
    float fx = 0.f, fy = 0.f, fz = 0.f, en = 0.f;
    if (i < n_atoms) {
        int c = i >> CHUNK_LOG;
        int l = i & (CHUNK - 1);
        const float4* base = (const float4*)partial + (size_t)c * n_slices * CHUNK + l;
        for (int p = 0; p < n_slices; ++p) {
            float4 v = base[(size_t)p * CHUNK];
            fx += v.x; fy += v.y; fz += v.z; en += v.w;
        }
        force[3 * i + 0] = fx;
        force[3 * i + 1] = fy;
        force[3 * i + 2] = fz;
    }
    int ic = i < n_atoms ? i : (n_atoms - 1);
    int b = batch[ic];
    float v = (i < n_atoms) ? en : 0.0f;
    int b0 = __shfl(b, 0, 64);
    unsigned long long m = __ballot(b == b0);
    if (m == ~0ull) {
        for (int off = 32; off > 0; off >>= 1)
            v += __shfl_down(v, off, 64);
        if ((threadIdx.x & 63) == 0) atomicAdd(&energy[b0], v);
    } else {
        atomicAdd(&energy[b], v);
    }
}

extern "C" void kernel_launch(void* const* d_in, const int* in_sizes, int n_in,
                              void* d_out, int out_size, void* d_ws, size_t ws_size,
                              hipStream_t stream) {
    const float* dij     = (const float*)d_in[0];
    const float* q       = (const float*)d_in[1];
    const float* g_ewald = (const float*)d_in[2];
    const int*   row     = (const int*)d_in[3];
    const int*   col     = (const int*)d_in[4];
    const int*   batch   = (const int*)d_in[5];

    int n_edges = in_sizes[0] / 3;
    int n_atoms = in_sizes[1];

    float* energy = (float*)d_out;               // [256]
    float* force  = (float*)d_out + N_GRAPHS_C;  // [n_atoms*3]

    int nb = (n_atoms + CHUNK - 1) >> CHUNK_LOG;            // 49
    int n4 = n_edges >> 2;

    size_t sz_fint    = (size_t)3 * n_atoms * sizeof(int);   // 2.4 MB
    size_t sz_ovf     = (size_t)3 * n_atoms * sizeof(float);
    size_t sz_qg      = (size_t)n_atoms * sizeof(float2);

    // Adaptive tile selection. nb=49 buckets: tile 1024 -> mean 167/run,
    // sigma ~13 -> cap 256 is +7 sigma; tile 2048 -> mean 334, cap 512 = +10.
    // Rare overflow goes through ovf atomics (still correct).
    const int  tile_sel[2]   = {1024, 2048};
    const int  mincap_sel[2] = {224, 416};
    const int  capmax_sel[2] = {256, 512};

    int tile_g = 0, cap = 0, nblkA = 0;
    size_t sz_epart = 0, sz_cnt = 0;
    for (int t = 0; t < 2 && tile_g == 0; ++t) {
        int nba = (n4 + tile_sel[t] - 1) / tile_sel[t];
        size_t se = (size_t)nba * N_GRAPHS_C * sizeof(float);
        size_t sc = (size_t)nba * nb * sizeof(unsigned);
        size_t fixed = ((sz_fint + 255) & ~(size_t)255) +
                       ((se      + 255) & ~(size_t)255) +
                       ((sc      + 255) & ~(size_t)255) +
                       ((sz_ovf  + 255) & ~(size_t)255) +
                       ((sz_qg   + 255) & ~(size_t)255) + 512;
        if ((long long)ws_size > (long long)fixed) {
            long long c = ((long long)ws_size - (long long)fixed) /
                          ((long long)nba * nb * 8);
            c = (c / 32) * 32;
            if (c > capmax_sel[t]) c = capmax_sel[t];
            if (c >= mincap_sel[t]) {
                tile_g = tile_sel[t]; cap = (int)c; nblkA = nba;
                sz_epart = se; sz_cnt = sc;
            }
        }
    }

    bool fast = (nb <= MAXB) && ((n_edges & 3) == 0) && (tile_g > 0) &&
                ((tile_g % TPA) == 0);

    if (fast) {
        char* ws = (char*)d_ws;
        size_t off = 0;
        uint2*    records  = (uint2*)(ws + off);
        off += (size_t)nblkA * nb * cap * 8;   off = (off + 255) & ~(size_t)255;
        int*      fint     = (int*)(ws + off);
        off += sz_fint;                        off = (off + 255) & ~(size_t)255;
        float*    e_part   = (float*)(ws + off);
        off += sz_epart;                       off = (off + 255) & ~(size_t)255;
        unsigned* cnt_tab  = (unsigned*)(ws + off);
        off += sz_cnt;                         off = (off + 255) & ~(size_t)255;
        float*    ovf      = (float*)(ws + off);
        off += sz_ovf;                         off = (off + 255) & ~(size_t)255;
        float2*   qg       = (float2*)(ws + off);

        prep_qg<<<(n_atoms + 255) / 256, 256, 0, stream>>>(
            q, batch, qg, ovf, fint, n_atoms);

        passA<<<nblkA, TPA, 0, stream>>>(
            dij, qg, g_ewald, row, col,
            records, cap, cnt_tab, e_part, ovf, n_edges, nb, tile_g);

        passB<<<nb * NSLICE, TPBB, 0, stream>>>(
            records, cap, cnt_tab, fint, nblkA, nb, NSLICE, n_atoms);

        int nfblk = (n_atoms + 255) / 256;
        fin_force<<<nfblk + N_GRAPHS_C / 4, 256, 0, stream>>>(
            fint, ovf, e_part, force, energy, n_atoms, nblkA, nfblk);
    } else {
        size_t need_chunk = (size_t)nb * NSLICE_FB * CHUNK * 4 * sizeof(float);
        if (ws_size >= need_chunk) {
            hipMemsetAsync(d_out, 0, N_GRAPHS_C * sizeof(float), stream);
            chunk_kernel<<<nb * NSLICE_FB, 1024, 0, stream>>>(
                dij, q, g_ewald, row, col, (float*)d_ws, n_edges, nb, NSLICE_FB);
            finalize_kernel<<<(n_atoms + 255) / 256, 256, 0, stream>>>(
                (const float*)d_ws, batch, energy, force, n_atoms, NSLICE_FB);
        }
    }
}